// Round 5
// baseline (5602.950 us; speedup 1.0000x reference)
//
#include <hip/hip_runtime.h>

// ---------------------------------------------------------------------------
// BiLSTM + CRF loss, MI355X — round 10.
// r9 -> r10:
//  (1) Skewed MFMA/cell pipeline: mfma pair for tile mt+2 issues right before
//      the cell update for tile mt -> activation VALU runs in the matrix
//      pipe's shadow (step ~ max(VALU,MFMA) instead of sum).
//  (2) s_setprio(1) on recurrence waves: worker blocks colocate at 128 VGPR
//      (4 waves/SIMD) and steal issue slots; priority protects the serial
//      chain during the overlap window.
//  (3) crf_pass: logsumexp via lane-0 normalizer (1 shfl) instead of 3-shfl
//      max-reduce; spread of score across 8 states is mixing-bounded so exp
//      cannot overflow.
// ---------------------------------------------------------------------------

constexpr int T_ = 2048, D_ = 256, K_ = 8;

typedef __bf16 v8bf __attribute__((ext_vector_type(8)));
typedef float  v4f  __attribute__((ext_vector_type(4)));
typedef int    v8i  __attribute__((ext_vector_type(8)));
typedef unsigned int u32;
typedef unsigned long long u64;

union U64x4 { u64 q[4]; v8i v; };

__device__ __forceinline__ float sigm(float x) {
  return __builtin_amdgcn_rcpf(1.f + __expf(-x));
}
__device__ __forceinline__ float tanh_f(float x) {
  return 1.f - 2.f * __builtin_amdgcn_rcpf(__expf(2.f * x) + 1.f);
}

__device__ __forceinline__ u32 pk2bf(float a, float b) {
  union { __bf16 h[2]; u32 u; } x; x.h[0] = (__bf16)a; x.h[1] = (__bf16)b; return x.u;
}
__device__ __forceinline__ float lobf(u32 u) { union { u32 u; __bf16 h[2]; } x; x.u = u; return (float)x.h[0]; }
__device__ __forceinline__ float hibf(u32 u) { union { u32 u; __bf16 h[2]; } x; x.u = u; return (float)x.h[1]; }

// packed row p = 16*mtg + rr, rr = 4*q + reg
//   -> gate reg, h-elem 32*(mtg>>3) + 8*(rr>>2) + (mtg&7)   [= 32w + 8q + mt]
__device__ __forceinline__ int gate_row(int mtg, int rr) {
  return (rr & 3) * 256 + 32 * (mtg >> 3) + 8 * (rr >> 2) + (mtg & 7);
}

// ws layout:
//   0x000000 wh8    fp8 w_hh  [d][mtg64][kt8][lane64] u64   512 KB
//   0x080000 wt16   bf16 w_tag frags [d][kt8][lane64] 16B    16 KB
//   0x084000 biasp  f32 [d][1024] permuted                    8 KB
//   0x086000 hstate bf16 [slot4][16][256]                    32 KB
//   0x08E000 cstate f32 [slot4][512][8]                      64 KB
//   0x100000 emisF  bf16 [32][2048][8]   0x200000 emisB       1 MB each
//   0x300000 pre    bf16 [slot2][d][CT][32][1024]            2 * CT*128 KB
//   after   hbuf    bf16 [slot2][d][CT][32][256]             2 * CT*16 KB

__global__ __launch_bounds__(256) void prepack(
    const float* __restrict__ w_hh_f, const float* __restrict__ w_hh_b,
    const float* __restrict__ b_ih_f, const float* __restrict__ b_hh_f,
    const float* __restrict__ b_ih_b, const float* __restrict__ b_hh_b,
    const float* __restrict__ w_tag,
    u64* wh8, v8bf* wt16, float* biasp, u32* hstate_u, float* cstate)
{
  int gid = blockIdx.x * 256 + threadIdx.x;
  if (gid < 65536) {                      // (a) w_hh -> fp8 frags for 16x16x128
    int lane = gid & 63, kt = (gid >> 6) & 7, mtg = (gid >> 9) & 63, d = gid >> 15;
    int rr = lane & 15, q = lane >> 4;
    const float* whh = d ? w_hh_b : w_hh_f;
    // k-map: k = 128*(kt>>2) + 32*q + 8*(kt&3) + byte  (identity h8l layout)
    const float* src = whh + (size_t)gate_row(mtg, rr) * 256
                           + 128 * (kt >> 2) + 32 * q + 8 * (kt & 3);
    u32 lo = __builtin_amdgcn_cvt_pk_fp8_f32(src[0], src[1], 0, false);
    lo = __builtin_amdgcn_cvt_pk_fp8_f32(src[2], src[3], lo, true);
    u32 hi = __builtin_amdgcn_cvt_pk_fp8_f32(src[4], src[5], 0, false);
    hi = __builtin_amdgcn_cvt_pk_fp8_f32(src[6], src[7], hi, true);
    wh8[gid] = ((u64)hi << 32) | lo;
  } else if (gid < 66560) {               // (b) w_tag frags (rows 8..15 zero)
    int g = gid - 65536;
    int lane = g & 63, kt = (g >> 6) & 7, d = (g >> 9) & 1;
    int rr = lane & 15, q = lane >> 4;
    v8bf v;
    #pragma unroll
    for (int e = 0; e < 8; ++e)
      v[e] = (rr < 8) ? (__bf16)w_tag[(size_t)rr * 512 + d * 256 + 32 * kt + 8 * q + e]
                      : (__bf16)0.f;
    wt16[g] = v;
  } else if (gid < 68608) {               // (c) permuted bias
    int g = gid - 66560;
    int p = g & 1023, d = g >> 10;
    int gr = gate_row(p >> 4, p & 15);
    biasp[g] = (d ? b_ih_b[gr] + b_hh_b[gr] : b_ih_f[gr] + b_hh_f[gr]);
  } else if (gid < 76800) {               // (d) zero hstate (32 KB = 8192 u32)
    hstate_u[gid - 68608] = 0u;
  } else if (gid < 93184) {               // (e) zero cstate (64 KB = 16384 f32)
    cstate[gid - 76800] = 0.f;
  }
}

// One kernel per chunk:
//   blocks [0,4)            : recurrence for chunk crec (writes h to hbuf)
//   blocks [4, 4+NPREB)     : pre = x @ W_ih^T + bias for chunk cpre
//   blocks [4+NPREB, ...)   : emission GEMM for chunk cemis (reads hbuf)
__global__ __launch_bounds__(512, 2) void fused_chunk(
    const float* __restrict__ sent, const int* __restrict__ lengths,
    const float* __restrict__ w_ih_f, const float* __restrict__ w_ih_b,
    const float* __restrict__ biasp,
    const u64* __restrict__ wh8, const v8bf* __restrict__ wt16,
    __bf16* __restrict__ hstate, float* __restrict__ cstate,
    __bf16* __restrict__ pre, __bf16* __restrict__ hbuf,
    __bf16* __restrict__ emisF, __bf16* __restrict__ emisB,
    int crec, int cpre, int cemis, int CT, int TT, int nch, int NPREB)
{
  __shared__ __align__(16) char smem[33792];

  if (blockIdx.x < 4) {
    if (crec < 0) return;
    // ---------------- recurrence ----------------
    __builtin_amdgcn_s_setprio(1);
    const int s = blockIdx.x, d = s >> 1, bg = s & 1;
    const int tid = threadIdx.x, lane = tid & 63, w = tid >> 6;
    const int fm = lane & 15, q = lane >> 4;
    int Lmax = 0;
    for (int i = 0; i < 32; ++i) Lmax = max(Lmax, lengths[i]);
    const int t0 = crec * CT, t1 = t0 + CT;
    const int tend = min(t1, Lmax);

    unsigned char* h8l = (unsigned char*)smem;      // [2][16*272] bytes (8704)

    // seed h (parity 1 = (t0-1)&1, t0 even) from hstate
    {
      int off = tid * 8, bb = off >> 8, e = off & 255;
      uint4 hv = *(const uint4*)(hstate + (size_t)s * 4096 + off);
      float f0 = lobf(hv.x), f1 = hibf(hv.x), f2 = lobf(hv.y), f3 = hibf(hv.y);
      float f4 = lobf(hv.z), f5 = hibf(hv.z), f6 = lobf(hv.w), f7 = hibf(hv.w);
      u32 lo = __builtin_amdgcn_cvt_pk_fp8_f32(f0, f1, 0, false);
      lo = __builtin_amdgcn_cvt_pk_fp8_f32(f2, f3, lo, true);
      u32 hi = __builtin_amdgcn_cvt_pk_fp8_f32(f4, f5, 0, false);
      hi = __builtin_amdgcn_cvt_pk_fp8_f32(f6, f7, hi, true);
      *(u64*)&h8l[4352 + bb * 272 + e] = ((u64)hi << 32) | lo;
    }

    // W_hh fp8 A-frags for 16x16x128 (two K-halves), 128 VGPR/AGPR
    v8i afr0[8], afr1[8];
    #pragma unroll
    for (int mt = 0; mt < 8; ++mt) {
      int mtg = 8 * w + mt;
      U64x4 lo, hi;
      #pragma unroll
      for (int jj = 0; jj < 4; ++jj) {
        lo.q[jj] = wh8[((size_t)(d * 64 + mtg) * 8 + jj) * 64 + lane];
        hi.q[jj] = wh8[((size_t)(d * 64 + mtg) * 8 + 4 + jj) * 64 + lane];
      }
      afr0[mt] = lo.v; afr1[mt] = hi.v;
    }
    float c8[8];
    #pragma unroll
    for (int mt = 0; mt < 8; ++mt) c8[mt] = cstate[((size_t)s * 512 + tid) * 8 + mt];

    const char* preBase = (const char*)pre + (size_t)(crec & 1) * CT * 131072;
    __bf16* hslot = hbuf + ((size_t)(crec & 1) * 2 + d) * CT * 8192;

    // prime the pre pipeline for step t0
    uint2 pA[8];
    {
      const char* pb = preBase + (((size_t)d * CT * 32 + (bg * 16 + fm)) * 1024) * 2;
      #pragma unroll
      for (int mt = 0; mt < 8; ++mt)
        pA[mt] = *(const uint2*)(pb + (16 * (8 * w + mt) + 4 * q) * 2);
    }

    uint4 hv4;   // this thread's 8 h values (bf16), elems 32w+8q..+7
    hv4.x = 0u; hv4.y = 0u; hv4.z = 0u; hv4.w = 0u;

    for (int t = t0; t < tend; ++t) {
      asm volatile("s_waitcnt lgkmcnt(0)" ::: "memory");
      __builtin_amdgcn_s_barrier();

      // gates accumulator initialized from pre (C-in of the MFMA)
      v4f acc[8];
      #pragma unroll
      for (int mt = 0; mt < 8; ++mt)
        acc[mt] = v4f{lobf(pA[mt].x), hibf(pA[mt].x), lobf(pA[mt].y), hibf(pA[mt].y)};

      // prefetch next step's pre (consumed at top of step t+1)
      uint2 pN[8];
      {
        int tn = min(t + 1, tend - 1);
        const char* pb = preBase +
            ((((size_t)d * CT + (tn - t0)) * 32 + (bg * 16 + fm)) * 1024) * 2;
        #pragma unroll
        for (int mt = 0; mt < 8; ++mt)
          pN[mt] = *(const uint2*)(pb + (16 * (8 * w + mt) + 4 * q) * 2);
      }

      const int pp = (t + 1) & 1;
      // B-frags: identity byte layout -> two contiguous 32B LDS reads
      v8i b0 = *(const v8i*)&h8l[pp * 4352 + fm * 272 + 32 * q];
      v8i b1 = *(const v8i*)&h8l[pp * 4352 + fm * 272 + 128 + 32 * q];

      // skewed pipeline: mfma pair for mt+2 issues before cell update of mt,
      // so activation VALU runs in the matrix pipe's shadow.
      acc[0] = __builtin_amdgcn_mfma_scale_f32_16x16x128_f8f6f4(
          afr0[0], b0, acc[0], 0, 0, 0, 0x7f7f7f7f, 0, 0x7f7f7f7f);
      acc[0] = __builtin_amdgcn_mfma_scale_f32_16x16x128_f8f6f4(
          afr1[0], b1, acc[0], 0, 0, 0, 0x7f7f7f7f, 0, 0x7f7f7f7f);
      acc[1] = __builtin_amdgcn_mfma_scale_f32_16x16x128_f8f6f4(
          afr0[1], b0, acc[1], 0, 0, 0, 0x7f7f7f7f, 0, 0x7f7f7f7f);
      acc[1] = __builtin_amdgcn_mfma_scale_f32_16x16x128_f8f6f4(
          afr1[1], b1, acc[1], 0, 0, 0, 0x7f7f7f7f, 0, 0x7f7f7f7f);

      float hh[8];
      #pragma unroll
      for (int mt = 0; mt < 8; ++mt) {
        if (mt + 2 < 8) {
          acc[mt + 2] = __builtin_amdgcn_mfma_scale_f32_16x16x128_f8f6f4(
              afr0[mt + 2], b0, acc[mt + 2], 0, 0, 0, 0x7f7f7f7f, 0, 0x7f7f7f7f);
          acc[mt + 2] = __builtin_amdgcn_mfma_scale_f32_16x16x128_f8f6f4(
              afr1[mt + 2], b1, acc[mt + 2], 0, 0, 0, 0x7f7f7f7f, 0, 0x7f7f7f7f);
        }
        float gi = acc[mt][0], gf = acc[mt][1], gg = acc[mt][2], go = acc[mt][3];
        float c = sigm(gf) * c8[mt] + sigm(gi) * tanh_f(gg);
        c8[mt] = c;
        hh[mt] = sigm(go) * tanh_f(c);
      }

      // publish fp8 h to LDS: single ds_write_b64
      {
        u32 lo = __builtin_amdgcn_cvt_pk_fp8_f32(hh[0], hh[1], 0, false);
        lo = __builtin_amdgcn_cvt_pk_fp8_f32(hh[2], hh[3], lo, true);
        u32 hi = __builtin_amdgcn_cvt_pk_fp8_f32(hh[4], hh[5], 0, false);
        hi = __builtin_amdgcn_cvt_pk_fp8_f32(hh[6], hh[7], hi, true);
        *(u64*)&h8l[(t & 1) * 4352 + fm * 272 + 32 * w + 8 * q] = ((u64)hi << 32) | lo;
      }
      // bf16 h -> hbuf, direct 16B store (fire-and-forget)
      hv4.x = pk2bf(hh[0], hh[1]); hv4.y = pk2bf(hh[2], hh[3]);
      hv4.z = pk2bf(hh[4], hh[5]); hv4.w = pk2bf(hh[6], hh[7]);
      *(uint4*)(hslot + ((size_t)(t - t0) * 32 + bg * 16 + fm) * 256 + 32 * w + 8 * q) = hv4;

      #pragma unroll
      for (int mt = 0; mt < 8; ++mt) pA[mt] = pN[mt];
    }

    // save state for the next chunk
    if (tend > t0) {
      #pragma unroll
      for (int mt = 0; mt < 8; ++mt) cstate[((size_t)s * 512 + tid) * 8 + mt] = c8[mt];
      *(uint4*)(hstate + (size_t)s * 4096 + fm * 256 + 32 * w + 8 * q) = hv4;
    }
    return;
  }

  if ((int)blockIdx.x < 4 + NPREB) {
    // ---------------- pre part: x @ W_ih^T + bias for chunk cpre ----------------
    if (cpre >= nch) return;
    const int u = (blockIdx.x - 4) * 2 + (threadIdx.x >> 8);
    const int b = u & 31, d = (u >> 5) & 1, zz = u >> 6;
    const int tg = zz >> 2, rg = zz & 3;
    const int tid = threadIdx.x & 255, lane = tid & 63, w = tid >> 6;
    const int fm = lane & 15, q = lane >> 4;
    const int NT = TT >> 4;
    const int t0 = cpre * CT;
    const int Lb = lengths[b];
    const float* wih = d ? w_ih_b : w_ih_f;
    __bf16* xl = (__bf16*)(smem + (threadIdx.x >> 8) * 16896);
    __bf16* preS = pre + (size_t)(cpre & 1) * CT * 65536;

    for (int rep = 0; rep < NT; ++rep) {
      int tl = (tid >> 4) + 16 * rep, c16 = (tid & 15) * 16;
      int tglob = t0 + TT * tg + tl;
      int pos = d ? ((tglob < Lb) ? (Lb - 1 - tglob) : tglob) : tglob;
      const float4* xp = (const float4*)(sent + ((size_t)b * T_ + pos) * D_ + c16);
      float4 a0 = xp[0], a1 = xp[1], a2 = xp[2], a3 = xp[3];
      v8bf v0, v1;
      v0[0]=(__bf16)a0.x; v0[1]=(__bf16)a0.y; v0[2]=(__bf16)a0.z; v0[3]=(__bf16)a0.w;
      v0[4]=(__bf16)a1.x; v0[5]=(__bf16)a1.y; v0[6]=(__bf16)a1.z; v0[7]=(__bf16)a1.w;
      v1[0]=(__bf16)a2.x; v1[1]=(__bf16)a2.y; v1[2]=(__bf16)a2.z; v1[3]=(__bf16)a2.w;
      v1[4]=(__bf16)a3.x; v1[5]=(__bf16)a3.y; v1[6]=(__bf16)a3.z; v1[7]=(__bf16)a3.w;
      *(v8bf*)&xl[tl * 264 + c16]     = v0;
      *(v8bf*)&xl[tl * 264 + c16 + 8] = v1;
    }

    v8bf af[4][8];
    v4f acc[4][2];
    #pragma unroll
    for (int mt = 0; mt < 4; ++mt) {
      int mtg = 16 * rg + 4 * w + mt;
      const float* src = wih + (size_t)gate_row(mtg, fm) * 256 + 8 * q;
      #pragma unroll
      for (int kt = 0; kt < 8; ++kt) {
        float4 a = *(const float4*)(src + 32 * kt);
        float4 b2 = *(const float4*)(src + 32 * kt + 4);
        v8bf v;
        v[0]=(__bf16)a.x;  v[1]=(__bf16)a.y;  v[2]=(__bf16)a.z;  v[3]=(__bf16)a.w;
        v[4]=(__bf16)b2.x; v[5]=(__bf16)b2.y; v[6]=(__bf16)b2.z; v[7]=(__bf16)b2.w;
        af[mt][kt] = v;
      }
      float4 bs = *(const float4*)(biasp + d * 1024 + 16 * mtg + 4 * q);
      for (int nt = 0; nt < 2; ++nt) acc[mt][nt] = v4f{bs.x, bs.y, bs.z, bs.w};
    }
    __syncthreads();

    for (int kt = 0; kt < 8; ++kt) {
      for (int nt = 0; nt < NT; ++nt) {
        v8bf bfr = *(const v8bf*)&xl[(nt * 16 + fm) * 264 + 32 * kt + 8 * q];
        #pragma unroll
        for (int mt = 0; mt < 4; ++mt)
          acc[mt][nt] = __builtin_amdgcn_mfma_f32_16x16x32_bf16(af[mt][kt], bfr, acc[mt][nt], 0, 0, 0);
      }
    }

    #pragma unroll
    for (int mt = 0; mt < 4; ++mt) {
      int mtg = 16 * rg + 4 * w + mt;
      for (int nt = 0; nt < NT; ++nt) {
        int tl = TT * tg + nt * 16 + fm;
        uint2 pk;
        pk.x = pk2bf(acc[mt][nt][0], acc[mt][nt][1]);
        pk.y = pk2bf(acc[mt][nt][2], acc[mt][nt][3]);
        size_t off = (((size_t)d * CT + tl) * 32 + b) * 1024 + 16 * mtg + 4 * q;
        *(uint2*)((char*)preS + off * 2) = pk;
      }
    }
    return;
  }

  // ---------------- emission part: emis = h @ w_tag^T for chunk cemis ----------
  if (cemis < 0) return;
  {
    const int eb = blockIdx.x - 4 - NPREB;
    const int u = eb * 8 + (threadIdx.x >> 6);
    const int b = u & 31, d2 = (u >> 5) & 1, tg2 = u >> 6;
    if (tg2 >= CT / 16) return;
    const int lane = threadIdx.x & 63, fm = lane & 15, q = lane >> 4;
    const int Ln = lengths[b];
    const int tl = tg2 * 16 + fm;     // local timestep = N-column
    const __bf16* hrow = hbuf + ((((size_t)(cemis & 1) * 2 + d2) * CT + tl) * 32 + b) * 256;
    v4f ea = {0.f, 0.f, 0.f, 0.f};
    #pragma unroll
    for (int kt = 0; kt < 8; ++kt) {
      v8bf wa = wt16[((size_t)d2 * 8 + kt) * 64 + lane];
      v8bf hb = *(const v8bf*)(hrow + 32 * kt + 8 * q);
      ea = __builtin_amdgcn_mfma_f32_16x16x32_bf16(wa, hb, ea, 0, 0, 0);
    }
    int se = cemis * CT + tl;
    if (q < 2 && se < Ln) {
      int pos = d2 ? (Ln - 1 - se) : se;
      __bf16* emis = d2 ? emisB : emisF;
      uint2 pk; pk.x = pk2bf(ea[0], ea[1]); pk.y = pk2bf(ea[2], ea[3]);
      *(uint2*)((char*)emis + (((size_t)b * T_ + pos) * K_ + 4 * q) * 2) = pk;
    }
  }
}

// CRF: one wave per batch; lanes = (j = l>>3 prev-state, k = l&7 next-state).
__global__ __launch_bounds__(64) void crf_pass(
    const int* __restrict__ lengths, const int* __restrict__ tags,
    const float* __restrict__ b_tag, const float* __restrict__ start_trans,
    const float* __restrict__ end_trans, const float* __restrict__ trans,
    const __bf16* __restrict__ emisF, const __bf16* __restrict__ emisB, float* out)
{
  int b = blockIdx.x;
  int l = threadIdx.x;
  int L = lengths[b];
  int j = l >> 3, k = l & 7;
  float trl = trans[j * 8 + k];
  float btk = b_tag[k];
  const __bf16* eF = emisF + (size_t)b * T_ * K_;
  const __bf16* eB = emisB + (size_t)b * T_ * K_;
  const uint4* pF = (const uint4*)eF;
  const uint4* pB = (const uint4*)eB;

  __shared__ float buf[2][64][16];
  {
    uint4 uF = pF[l], uB = pB[l];
    float* r = &buf[0][l][0];
    r[0]=lobf(uF.x); r[1]=hibf(uF.x); r[2]=lobf(uF.y); r[3]=hibf(uF.y);
    r[4]=lobf(uF.z); r[5]=hibf(uF.z); r[6]=lobf(uF.w); r[7]=hibf(uF.w);
    r[8]=lobf(uB.x); r[9]=hibf(uB.x); r[10]=lobf(uB.y); r[11]=hibf(uB.y);
    r[12]=lobf(uB.z); r[13]=hibf(uB.z); r[14]=lobf(uB.w); r[15]=hibf(uB.w);
  }
  __syncthreads();

  float score = start_trans[j] + buf[0][0][j] + buf[0][0][8 + j] + b_tag[j];
  int nch = (L + 63) >> 6;
  for (int c = 0; c < nch; ++c) {
    uint4 preF, preB;
    bool more = (c + 1 < nch);
    if (more) { preF = pF[64 * (c + 1) + l]; preB = pB[64 * (c + 1) + l]; }
    int cur = c & 1;
    int tendc = min(64, L - 64 * c);
    for (int tt = (c == 0 ? 1 : 0); tt < tendc; ++tt) {
      float e = buf[cur][tt][k] + buf[cur][tt][8 + k] + btk;
      // logsumexp with lane-0 normalizer (score spread is mixing-bounded)
      float m = __shfl(score, 0);
      float p = __expf(score + trl - m);
      p += __shfl_xor(p, 8); p += __shfl_xor(p, 16); p += __shfl_xor(p, 32);
      score = __shfl(m + __logf(p) + e, j);
    }
    if (more) {
      __syncthreads();
      float* r = &buf[cur ^ 1][l][0];
      r[0]=lobf(preF.x); r[1]=hibf(preF.x); r[2]=lobf(preF.y); r[3]=hibf(preF.y);
      r[4]=lobf(preF.z); r[5]=hibf(preF.z); r[6]=lobf(preF.w); r[7]=hibf(preF.w);
      r[8]=lobf(preB.x); r[9]=hibf(preB.x); r[10]=lobf(preB.y); r[11]=hibf(preB.y);
      r[12]=lobf(preB.z); r[13]=hibf(preB.z); r[14]=lobf(preB.w); r[15]=hibf(preB.w);
      __syncthreads();
    }
  }

  float v = score + end_trans[j];
  float m = fmaxf(v, __shfl_xor(v, 8)); m = fmaxf(m, __shfl_xor(m, 16)); m = fmaxf(m, __shfl_xor(m, 32));
  float p = __expf(v - m);
  p += __shfl_xor(p, 8); p += __shfl_xor(p, 16); p += __shfl_xor(p, 32);
  float logZ = m + __logf(p);

  const int* tg = tags + (size_t)b * T_;
  float nsum = 0.f;
  for (int t = l; t < L; t += 64) {
    int tt = tg[t];
    float e = (float)eF[t * 8 + tt] + (float)eB[t * 8 + tt] + b_tag[tt];
    float tr = (t > 0) ? trans[tg[t - 1] * 8 + tt] : 0.f;
    nsum += e + tr;
  }
  nsum += __shfl_xor(nsum, 1);  nsum += __shfl_xor(nsum, 2);  nsum += __shfl_xor(nsum, 4);
  nsum += __shfl_xor(nsum, 8);  nsum += __shfl_xor(nsum, 16); nsum += __shfl_xor(nsum, 32);
  if (l == 0) {
    float num = nsum + start_trans[tg[0]] + end_trans[tg[L - 1]];
    atomicAdd(out, (logZ - num) * (1.f / 32.f));
  }
}

extern "C" void kernel_launch(void* const* d_in, const int* in_sizes, int n_in,
                              void* d_out, int out_size, void* d_ws, size_t ws_size,
                              hipStream_t stream) {
  (void)in_sizes; (void)n_in; (void)out_size;
  const float* sent        = (const float*)d_in[0];
  const int*   tags        = (const int*)d_in[1];
  const int*   lengths     = (const int*)d_in[2];
  // d_in[3] = mask (unused)
  const float* w_ih_f      = (const float*)d_in[4];
  const float* w_hh_f      = (const float*)d_in[5];
  const float* b_ih_f      = (const float*)d_in[6];
  const float* b_hh_f      = (const float*)d_in[7];
  const float* w_ih_b      = (const float*)d_in[8];
  const float* w_hh_b      = (const float*)d_in[9];
  const float* b_ih_b      = (const float*)d_in[10];
  const float* b_hh_b      = (const float*)d_in[11];
  const float* w_tag       = (const float*)d_in[12];
  const float* b_tag       = (const float*)d_in[13];
  const float* start_trans = (const float*)d_in[14];
  const float* end_trans   = (const float*)d_in[15];
  const float* trans       = (const float*)d_in[16];

  char* ws = (char*)d_ws;
  u64*    wh8    = (u64*)(ws + 0x000000);
  v8bf*   wt16   = (v8bf*)(ws + 0x080000);
  float*  biasp  = (float*)(ws + 0x084000);
  __bf16* hstate = (__bf16*)(ws + 0x086000);   // 32 KB (4 slots x 8 KB)
  float*  cstate = (float*)(ws + 0x08E000);    // 64 KB
  __bf16* emisF  = (__bf16*)(ws + 0x100000);
  __bf16* emisB  = (__bf16*)(ws + 0x200000);
  __bf16* pre    = (__bf16*)(ws + 0x300000);

  // largest CT whose double pre (CT*256KB) + double hbuf (CT*64KB) fits.
  int CT = 64;
  for (int cand : {256, 128}) {
    if ((size_t)0x300000 + (size_t)cand * (2 * 131072 + 2 * 32768) <= ws_size) { CT = cand; break; }
  }
  __bf16* hbuf = (__bf16*)(ws + 0x300000 + 2ull * (size_t)CT * 131072ull);
  const int TT = 32;
  const int nch = T_ / CT;
  const int NPREB = 128 * (CT / TT);   // 2 pre sub-units per block
  const int NEMIS = CT / 2;            // 8 emission waves per block
  dim3 grid(4 + NPREB + NEMIS, 1, 1);

  hipMemsetAsync(d_out, 0, sizeof(float), stream);
  prepack<<<364, 256, 0, stream>>>(w_hh_f, w_hh_b, b_ih_f, b_hh_f, b_ih_b, b_hh_b,
                                   w_tag, wh8, wt16, biasp, (u32*)hstate, cstate);
  // prime: pre for chunk 0 only
  fused_chunk<<<grid, 512, 0, stream>>>(sent, lengths, w_ih_f, w_ih_b, biasp, wh8, wt16,
                                        hstate, cstate, pre, hbuf, emisF, emisB,
                                        -1, 0, -1, CT, TT, nch, NPREB);
  for (int c = 0; c < nch; ++c)
    fused_chunk<<<grid, 512, 0, stream>>>(sent, lengths, w_ih_f, w_ih_b, biasp, wh8, wt16,
                                          hstate, cstate, pre, hbuf, emisF, emisB,
                                          c, c + 1, c - 1, CT, TT, nch, NPREB);
  // tail: emission for the last chunk
  fused_chunk<<<grid, 512, 0, stream>>>(sent, lengths, w_ih_f, w_ih_b, biasp, wh8, wt16,
                                        hstate, cstate, pre, hbuf, emisF, emisB,
                                        -1, nch, nch - 1, CT, TT, nch, NPREB);
  crf_pass<<<32, 64, 0, stream>>>(lengths, tags, b_tag, start_trans, end_trans, trans,
                                  emisF, emisB, (float*)d_out);
}

// Round 6
// 4350.065 us; speedup vs baseline: 1.2880x; 1.2880x over previous
//
#include <hip/hip_runtime.h>

// ---------------------------------------------------------------------------
// BiLSTM + CRF loss, MI355X — round 11.
// r10 -> r11:
//  (1) MFMA C-in dependency stalls removed: the two K-half MFMAs per mt were
//      adjacent+dependent (dep-distance 1; K=128 scaled MFMA latency >>
//      34.5cy throughput gap -> ~8 serial stalls/wave/step). Now TWO
//      independent accumulator sets (acc: C=pre, accb: C=0), grouped
//      [afr0 x mt=0..7][afr1 x mt=0..7]; cell update sums them.
//  (2) Revert r10 skew + setprio (measured -31us regression).
//  (3) Keep r10 crf lane-0-normalizer (measured ~ -150us, absmax 0).
// ---------------------------------------------------------------------------

constexpr int T_ = 2048, D_ = 256, K_ = 8;

typedef __bf16 v8bf __attribute__((ext_vector_type(8)));
typedef float  v4f  __attribute__((ext_vector_type(4)));
typedef int    v8i  __attribute__((ext_vector_type(8)));
typedef unsigned int u32;
typedef unsigned long long u64;

union U64x4 { u64 q[4]; v8i v; };

__device__ __forceinline__ float sigm(float x) {
  return __builtin_amdgcn_rcpf(1.f + __expf(-x));
}
__device__ __forceinline__ float tanh_f(float x) {
  return 1.f - 2.f * __builtin_amdgcn_rcpf(__expf(2.f * x) + 1.f);
}

__device__ __forceinline__ u32 pk2bf(float a, float b) {
  union { __bf16 h[2]; u32 u; } x; x.h[0] = (__bf16)a; x.h[1] = (__bf16)b; return x.u;
}
__device__ __forceinline__ float lobf(u32 u) { union { u32 u; __bf16 h[2]; } x; x.u = u; return (float)x.h[0]; }
__device__ __forceinline__ float hibf(u32 u) { union { u32 u; __bf16 h[2]; } x; x.u = u; return (float)x.h[1]; }

// packed row p = 16*mtg + rr, rr = 4*q + reg
//   -> gate reg, h-elem 32*(mtg>>3) + 8*(rr>>2) + (mtg&7)   [= 32w + 8q + mt]
__device__ __forceinline__ int gate_row(int mtg, int rr) {
  return (rr & 3) * 256 + 32 * (mtg >> 3) + 8 * (rr >> 2) + (mtg & 7);
}

// ws layout:
//   0x000000 wh8    fp8 w_hh  [d][mtg64][kt8][lane64] u64   512 KB
//   0x080000 wt16   bf16 w_tag frags [d][kt8][lane64] 16B    16 KB
//   0x084000 biasp  f32 [d][1024] permuted                    8 KB
//   0x086000 hstate bf16 [slot4][16][256]                    32 KB
//   0x08E000 cstate f32 [slot4][512][8]                      64 KB
//   0x100000 emisF  bf16 [32][2048][8]   0x200000 emisB       1 MB each
//   0x300000 pre    bf16 [slot2][d][CT][32][1024]            2 * CT*128 KB
//   after   hbuf    bf16 [slot2][d][CT][32][256]             2 * CT*16 KB

__global__ __launch_bounds__(256) void prepack(
    const float* __restrict__ w_hh_f, const float* __restrict__ w_hh_b,
    const float* __restrict__ b_ih_f, const float* __restrict__ b_hh_f,
    const float* __restrict__ b_ih_b, const float* __restrict__ b_hh_b,
    const float* __restrict__ w_tag,
    u64* wh8, v8bf* wt16, float* biasp, u32* hstate_u, float* cstate)
{
  int gid = blockIdx.x * 256 + threadIdx.x;
  if (gid < 65536) {                      // (a) w_hh -> fp8 frags for 16x16x128
    int lane = gid & 63, kt = (gid >> 6) & 7, mtg = (gid >> 9) & 63, d = gid >> 15;
    int rr = lane & 15, q = lane >> 4;
    const float* whh = d ? w_hh_b : w_hh_f;
    // k-map: k = 128*(kt>>2) + 32*q + 8*(kt&3) + byte  (identity h8l layout)
    const float* src = whh + (size_t)gate_row(mtg, rr) * 256
                           + 128 * (kt >> 2) + 32 * q + 8 * (kt & 3);
    u32 lo = __builtin_amdgcn_cvt_pk_fp8_f32(src[0], src[1], 0, false);
    lo = __builtin_amdgcn_cvt_pk_fp8_f32(src[2], src[3], lo, true);
    u32 hi = __builtin_amdgcn_cvt_pk_fp8_f32(src[4], src[5], 0, false);
    hi = __builtin_amdgcn_cvt_pk_fp8_f32(src[6], src[7], hi, true);
    wh8[gid] = ((u64)hi << 32) | lo;
  } else if (gid < 66560) {               // (b) w_tag frags (rows 8..15 zero)
    int g = gid - 65536;
    int lane = g & 63, kt = (g >> 6) & 7, d = (g >> 9) & 1;
    int rr = lane & 15, q = lane >> 4;
    v8bf v;
    #pragma unroll
    for (int e = 0; e < 8; ++e)
      v[e] = (rr < 8) ? (__bf16)w_tag[(size_t)rr * 512 + d * 256 + 32 * kt + 8 * q + e]
                      : (__bf16)0.f;
    wt16[g] = v;
  } else if (gid < 68608) {               // (c) permuted bias
    int g = gid - 66560;
    int p = g & 1023, d = g >> 10;
    int gr = gate_row(p >> 4, p & 15);
    biasp[g] = (d ? b_ih_b[gr] + b_hh_b[gr] : b_ih_f[gr] + b_hh_f[gr]);
  } else if (gid < 76800) {               // (d) zero hstate (32 KB = 8192 u32)
    hstate_u[gid - 68608] = 0u;
  } else if (gid < 93184) {               // (e) zero cstate (64 KB = 16384 f32)
    cstate[gid - 76800] = 0.f;
  }
}

// One kernel per chunk:
//   blocks [0,4)            : recurrence for chunk crec (writes h to hbuf)
//   blocks [4, 4+NPREB)     : pre = x @ W_ih^T + bias for chunk cpre
//   blocks [4+NPREB, ...)   : emission GEMM for chunk cemis (reads hbuf)
__global__ __launch_bounds__(512, 2) void fused_chunk(
    const float* __restrict__ sent, const int* __restrict__ lengths,
    const float* __restrict__ w_ih_f, const float* __restrict__ w_ih_b,
    const float* __restrict__ biasp,
    const u64* __restrict__ wh8, const v8bf* __restrict__ wt16,
    __bf16* __restrict__ hstate, float* __restrict__ cstate,
    __bf16* __restrict__ pre, __bf16* __restrict__ hbuf,
    __bf16* __restrict__ emisF, __bf16* __restrict__ emisB,
    int crec, int cpre, int cemis, int CT, int TT, int nch, int NPREB)
{
  __shared__ __align__(16) char smem[33792];

  if (blockIdx.x < 4) {
    if (crec < 0) return;
    // ---------------- recurrence ----------------
    const int s = blockIdx.x, d = s >> 1, bg = s & 1;
    const int tid = threadIdx.x, lane = tid & 63, w = tid >> 6;
    const int fm = lane & 15, q = lane >> 4;
    int Lmax = 0;
    for (int i = 0; i < 32; ++i) Lmax = max(Lmax, lengths[i]);
    const int t0 = crec * CT, t1 = t0 + CT;
    const int tend = min(t1, Lmax);

    unsigned char* h8l = (unsigned char*)smem;      // [2][16*272] bytes (8704)

    // seed h (parity 1 = (t0-1)&1, t0 even) from hstate
    {
      int off = tid * 8, bb = off >> 8, e = off & 255;
      uint4 hv = *(const uint4*)(hstate + (size_t)s * 4096 + off);
      float f0 = lobf(hv.x), f1 = hibf(hv.x), f2 = lobf(hv.y), f3 = hibf(hv.y);
      float f4 = lobf(hv.z), f5 = hibf(hv.z), f6 = lobf(hv.w), f7 = hibf(hv.w);
      u32 lo = __builtin_amdgcn_cvt_pk_fp8_f32(f0, f1, 0, false);
      lo = __builtin_amdgcn_cvt_pk_fp8_f32(f2, f3, lo, true);
      u32 hi = __builtin_amdgcn_cvt_pk_fp8_f32(f4, f5, 0, false);
      hi = __builtin_amdgcn_cvt_pk_fp8_f32(f6, f7, hi, true);
      *(u64*)&h8l[4352 + bb * 272 + e] = ((u64)hi << 32) | lo;
    }

    // W_hh fp8 A-frags for 16x16x128 (two K-halves), 128 VGPR/AGPR
    v8i afr0[8], afr1[8];
    #pragma unroll
    for (int mt = 0; mt < 8; ++mt) {
      int mtg = 8 * w + mt;
      U64x4 lo, hi;
      #pragma unroll
      for (int jj = 0; jj < 4; ++jj) {
        lo.q[jj] = wh8[((size_t)(d * 64 + mtg) * 8 + jj) * 64 + lane];
        hi.q[jj] = wh8[((size_t)(d * 64 + mtg) * 8 + 4 + jj) * 64 + lane];
      }
      afr0[mt] = lo.v; afr1[mt] = hi.v;
    }
    float c8[8];
    #pragma unroll
    for (int mt = 0; mt < 8; ++mt) c8[mt] = cstate[((size_t)s * 512 + tid) * 8 + mt];

    const char* preBase = (const char*)pre + (size_t)(crec & 1) * CT * 131072;
    __bf16* hslot = hbuf + ((size_t)(crec & 1) * 2 + d) * CT * 8192;

    // prime the pre pipeline for step t0
    uint2 pA[8];
    {
      const char* pb = preBase + (((size_t)d * CT * 32 + (bg * 16 + fm)) * 1024) * 2;
      #pragma unroll
      for (int mt = 0; mt < 8; ++mt)
        pA[mt] = *(const uint2*)(pb + (16 * (8 * w + mt) + 4 * q) * 2);
    }

    uint4 hv4;   // this thread's 8 h values (bf16), elems 32w+8q..+7
    hv4.x = 0u; hv4.y = 0u; hv4.z = 0u; hv4.w = 0u;

    for (int t = t0; t < tend; ++t) {
      asm volatile("s_waitcnt lgkmcnt(0)" ::: "memory");
      __builtin_amdgcn_s_barrier();

      // accumulator set A initialized from pre (C-in of the afr0 MFMAs)
      v4f acc[8];
      #pragma unroll
      for (int mt = 0; mt < 8; ++mt)
        acc[mt] = v4f{lobf(pA[mt].x), hibf(pA[mt].x), lobf(pA[mt].y), hibf(pA[mt].y)};
      // accumulator set B zero-initialized (C-in of the afr1 MFMAs)
      v4f accb[8];
      #pragma unroll
      for (int mt = 0; mt < 8; ++mt) accb[mt] = v4f{0.f, 0.f, 0.f, 0.f};

      // prefetch next step's pre (consumed at top of step t+1)
      uint2 pN[8];
      {
        int tn = min(t + 1, tend - 1);
        const char* pb = preBase +
            ((((size_t)d * CT + (tn - t0)) * 32 + (bg * 16 + fm)) * 1024) * 2;
        #pragma unroll
        for (int mt = 0; mt < 8; ++mt)
          pN[mt] = *(const uint2*)(pb + (16 * (8 * w + mt) + 4 * q) * 2);
      }

      const int pp = (t + 1) & 1;
      // B-frags: identity byte layout -> two contiguous 32B LDS reads
      v8i b0 = *(const v8i*)&h8l[pp * 4352 + fm * 272 + 32 * q];
      v8i b1 = *(const v8i*)&h8l[pp * 4352 + fm * 272 + 128 + 32 * q];

      // 16 mutually independent MFMAs (no C-in chains): all afr0 then all afr1
      #pragma unroll
      for (int mt = 0; mt < 8; ++mt)
        acc[mt] = __builtin_amdgcn_mfma_scale_f32_16x16x128_f8f6f4(
            afr0[mt], b0, acc[mt], 0, 0, 0, 0x7f7f7f7f, 0, 0x7f7f7f7f);
      #pragma unroll
      for (int mt = 0; mt < 8; ++mt)
        accb[mt] = __builtin_amdgcn_mfma_scale_f32_16x16x128_f8f6f4(
            afr1[mt], b1, accb[mt], 0, 0, 0, 0x7f7f7f7f, 0, 0x7f7f7f7f);

      // cell update; thread's 8 h-elems are contiguous at 32w+8q (mt fastest)
      float hh[8];
      #pragma unroll
      for (int mt = 0; mt < 8; ++mt) {
        float gi = acc[mt][0] + accb[mt][0];
        float gf = acc[mt][1] + accb[mt][1];
        float gg = acc[mt][2] + accb[mt][2];
        float go = acc[mt][3] + accb[mt][3];
        float c = sigm(gf) * c8[mt] + sigm(gi) * tanh_f(gg);
        c8[mt] = c;
        hh[mt] = sigm(go) * tanh_f(c);
      }

      // publish fp8 h to LDS: single ds_write_b64
      {
        u32 lo = __builtin_amdgcn_cvt_pk_fp8_f32(hh[0], hh[1], 0, false);
        lo = __builtin_amdgcn_cvt_pk_fp8_f32(hh[2], hh[3], lo, true);
        u32 hi = __builtin_amdgcn_cvt_pk_fp8_f32(hh[4], hh[5], 0, false);
        hi = __builtin_amdgcn_cvt_pk_fp8_f32(hh[6], hh[7], hi, true);
        *(u64*)&h8l[(t & 1) * 4352 + fm * 272 + 32 * w + 8 * q] = ((u64)hi << 32) | lo;
      }
      // bf16 h -> hbuf, direct 16B store (fire-and-forget)
      hv4.x = pk2bf(hh[0], hh[1]); hv4.y = pk2bf(hh[2], hh[3]);
      hv4.z = pk2bf(hh[4], hh[5]); hv4.w = pk2bf(hh[6], hh[7]);
      *(uint4*)(hslot + ((size_t)(t - t0) * 32 + bg * 16 + fm) * 256 + 32 * w + 8 * q) = hv4;

      #pragma unroll
      for (int mt = 0; mt < 8; ++mt) pA[mt] = pN[mt];
    }

    // save state for the next chunk
    if (tend > t0) {
      #pragma unroll
      for (int mt = 0; mt < 8; ++mt) cstate[((size_t)s * 512 + tid) * 8 + mt] = c8[mt];
      *(uint4*)(hstate + (size_t)s * 4096 + fm * 256 + 32 * w + 8 * q) = hv4;
    }
    return;
  }

  if ((int)blockIdx.x < 4 + NPREB) {
    // ---------------- pre part: x @ W_ih^T + bias for chunk cpre ----------------
    if (cpre >= nch) return;
    const int u = (blockIdx.x - 4) * 2 + (threadIdx.x >> 8);
    const int b = u & 31, d = (u >> 5) & 1, zz = u >> 6;
    const int tg = zz >> 2, rg = zz & 3;
    const int tid = threadIdx.x & 255, lane = tid & 63, w = tid >> 6;
    const int fm = lane & 15, q = lane >> 4;
    const int NT = TT >> 4;
    const int t0 = cpre * CT;
    const int Lb = lengths[b];
    const float* wih = d ? w_ih_b : w_ih_f;
    __bf16* xl = (__bf16*)(smem + (threadIdx.x >> 8) * 16896);
    __bf16* preS = pre + (size_t)(cpre & 1) * CT * 65536;

    for (int rep = 0; rep < NT; ++rep) {
      int tl = (tid >> 4) + 16 * rep, c16 = (tid & 15) * 16;
      int tglob = t0 + TT * tg + tl;
      int pos = d ? ((tglob < Lb) ? (Lb - 1 - tglob) : tglob) : tglob;
      const float4* xp = (const float4*)(sent + ((size_t)b * T_ + pos) * D_ + c16);
      float4 a0 = xp[0], a1 = xp[1], a2 = xp[2], a3 = xp[3];
      v8bf v0, v1;
      v0[0]=(__bf16)a0.x; v0[1]=(__bf16)a0.y; v0[2]=(__bf16)a0.z; v0[3]=(__bf16)a0.w;
      v0[4]=(__bf16)a1.x; v0[5]=(__bf16)a1.y; v0[6]=(__bf16)a1.z; v0[7]=(__bf16)a1.w;
      v1[0]=(__bf16)a2.x; v1[1]=(__bf16)a2.y; v1[2]=(__bf16)a2.z; v1[3]=(__bf16)a2.w;
      v1[4]=(__bf16)a3.x; v1[5]=(__bf16)a3.y; v1[6]=(__bf16)a3.z; v1[7]=(__bf16)a3.w;
      *(v8bf*)&xl[tl * 264 + c16]     = v0;
      *(v8bf*)&xl[tl * 264 + c16 + 8] = v1;
    }

    v8bf af[4][8];
    v4f acc[4][2];
    #pragma unroll
    for (int mt = 0; mt < 4; ++mt) {
      int mtg = 16 * rg + 4 * w + mt;
      const float* src = wih + (size_t)gate_row(mtg, fm) * 256 + 8 * q;
      #pragma unroll
      for (int kt = 0; kt < 8; ++kt) {
        float4 a = *(const float4*)(src + 32 * kt);
        float4 b2 = *(const float4*)(src + 32 * kt + 4);
        v8bf v;
        v[0]=(__bf16)a.x;  v[1]=(__bf16)a.y;  v[2]=(__bf16)a.z;  v[3]=(__bf16)a.w;
        v[4]=(__bf16)b2.x; v[5]=(__bf16)b2.y; v[6]=(__bf16)b2.z; v[7]=(__bf16)b2.w;
        af[mt][kt] = v;
      }
      float4 bs = *(const float4*)(biasp + d * 1024 + 16 * mtg + 4 * q);
      for (int nt = 0; nt < 2; ++nt) acc[mt][nt] = v4f{bs.x, bs.y, bs.z, bs.w};
    }
    __syncthreads();

    for (int kt = 0; kt < 8; ++kt) {
      for (int nt = 0; nt < NT; ++nt) {
        v8bf bfr = *(const v8bf*)&xl[(nt * 16 + fm) * 264 + 32 * kt + 8 * q];
        #pragma unroll
        for (int mt = 0; mt < 4; ++mt)
          acc[mt][nt] = __builtin_amdgcn_mfma_f32_16x16x32_bf16(af[mt][kt], bfr, acc[mt][nt], 0, 0, 0);
      }
    }

    #pragma unroll
    for (int mt = 0; mt < 4; ++mt) {
      int mtg = 16 * rg + 4 * w + mt;
      for (int nt = 0; nt < NT; ++nt) {
        int tl = TT * tg + nt * 16 + fm;
        uint2 pk;
        pk.x = pk2bf(acc[mt][nt][0], acc[mt][nt][1]);
        pk.y = pk2bf(acc[mt][nt][2], acc[mt][nt][3]);
        size_t off = (((size_t)d * CT + tl) * 32 + b) * 1024 + 16 * mtg + 4 * q;
        *(uint2*)((char*)preS + off * 2) = pk;
      }
    }
    return;
  }

  // ---------------- emission part: emis = h @ w_tag^T for chunk cemis ----------
  if (cemis < 0) return;
  {
    const int eb = blockIdx.x - 4 - NPREB;
    const int u = eb * 8 + (threadIdx.x >> 6);
    const int b = u & 31, d2 = (u >> 5) & 1, tg2 = u >> 6;
    if (tg2 >= CT / 16) return;
    const int lane = threadIdx.x & 63, fm = lane & 15, q = lane >> 4;
    const int Ln = lengths[b];
    const int tl = tg2 * 16 + fm;     // local timestep = N-column
    const __bf16* hrow = hbuf + ((((size_t)(cemis & 1) * 2 + d2) * CT + tl) * 32 + b) * 256;
    v4f ea = {0.f, 0.f, 0.f, 0.f};
    #pragma unroll
    for (int kt = 0; kt < 8; ++kt) {
      v8bf wa = wt16[((size_t)d2 * 8 + kt) * 64 + lane];
      v8bf hb = *(const v8bf*)(hrow + 32 * kt + 8 * q);
      ea = __builtin_amdgcn_mfma_f32_16x16x32_bf16(wa, hb, ea, 0, 0, 0);
    }
    int se = cemis * CT + tl;
    if (q < 2 && se < Ln) {
      int pos = d2 ? (Ln - 1 - se) : se;
      __bf16* emis = d2 ? emisB : emisF;
      uint2 pk; pk.x = pk2bf(ea[0], ea[1]); pk.y = pk2bf(ea[2], ea[3]);
      *(uint2*)((char*)emis + (((size_t)b * T_ + pos) * K_ + 4 * q) * 2) = pk;
    }
  }
}

// CRF: one wave per batch; lanes = (j = l>>3 prev-state, k = l&7 next-state).
__global__ __launch_bounds__(64) void crf_pass(
    const int* __restrict__ lengths, const int* __restrict__ tags,
    const float* __restrict__ b_tag, const float* __restrict__ start_trans,
    const float* __restrict__ end_trans, const float* __restrict__ trans,
    const __bf16* __restrict__ emisF, const __bf16* __restrict__ emisB, float* out)
{
  int b = blockIdx.x;
  int l = threadIdx.x;
  int L = lengths[b];
  int j = l >> 3, k = l & 7;
  float trl = trans[j * 8 + k];
  float btk = b_tag[k];
  const __bf16* eF = emisF + (size_t)b * T_ * K_;
  const __bf16* eB = emisB + (size_t)b * T_ * K_;
  const uint4* pF = (const uint4*)eF;
  const uint4* pB = (const uint4*)eB;

  __shared__ float buf[2][64][16];
  {
    uint4 uF = pF[l], uB = pB[l];
    float* r = &buf[0][l][0];
    r[0]=lobf(uF.x); r[1]=hibf(uF.x); r[2]=lobf(uF.y); r[3]=hibf(uF.y);
    r[4]=lobf(uF.z); r[5]=hibf(uF.z); r[6]=lobf(uF.w); r[7]=hibf(uF.w);
    r[8]=lobf(uB.x); r[9]=hibf(uB.x); r[10]=lobf(uB.y); r[11]=hibf(uB.y);
    r[12]=lobf(uB.z); r[13]=hibf(uB.z); r[14]=lobf(uB.w); r[15]=hibf(uB.w);
  }
  __syncthreads();

  float score = start_trans[j] + buf[0][0][j] + buf[0][0][8 + j] + b_tag[j];
  int nch = (L + 63) >> 6;
  for (int c = 0; c < nch; ++c) {
    uint4 preF, preB;
    bool more = (c + 1 < nch);
    if (more) { preF = pF[64 * (c + 1) + l]; preB = pB[64 * (c + 1) + l]; }
    int cur = c & 1;
    int tendc = min(64, L - 64 * c);
    for (int tt = (c == 0 ? 1 : 0); tt < tendc; ++tt) {
      float e = buf[cur][tt][k] + buf[cur][tt][8 + k] + btk;
      // logsumexp with lane-0 normalizer (score spread is mixing-bounded)
      float m = __shfl(score, 0);
      float p = __expf(score + trl - m);
      p += __shfl_xor(p, 8); p += __shfl_xor(p, 16); p += __shfl_xor(p, 32);
      score = __shfl(m + __logf(p) + e, j);
    }
    if (more) {
      __syncthreads();
      float* r = &buf[cur ^ 1][l][0];
      r[0]=lobf(preF.x); r[1]=hibf(preF.x); r[2]=lobf(preF.y); r[3]=hibf(preF.y);
      r[4]=lobf(preF.z); r[5]=hibf(preF.z); r[6]=lobf(preF.w); r[7]=hibf(preF.w);
      r[8]=lobf(preB.x); r[9]=hibf(preB.x); r[10]=lobf(preB.y); r[11]=hibf(preB.y);
      r[12]=lobf(preB.z); r[13]=hibf(preB.z); r[14]=lobf(preB.w); r[15]=hibf(preB.w);
      __syncthreads();
    }
  }

  float v = score + end_trans[j];
  float m = fmaxf(v, __shfl_xor(v, 8)); m = fmaxf(m, __shfl_xor(m, 16)); m = fmaxf(m, __shfl_xor(m, 32));
  float p = __expf(v - m);
  p += __shfl_xor(p, 8); p += __shfl_xor(p, 16); p += __shfl_xor(p, 32);
  float logZ = m + __logf(p);

  const int* tg = tags + (size_t)b * T_;
  float nsum = 0.f;
  for (int t = l; t < L; t += 64) {
    int tt = tg[t];
    float e = (float)eF[t * 8 + tt] + (float)eB[t * 8 + tt] + b_tag[tt];
    float tr = (t > 0) ? trans[tg[t - 1] * 8 + tt] : 0.f;
    nsum += e + tr;
  }
  nsum += __shfl_xor(nsum, 1);  nsum += __shfl_xor(nsum, 2);  nsum += __shfl_xor(nsum, 4);
  nsum += __shfl_xor(nsum, 8);  nsum += __shfl_xor(nsum, 16); nsum += __shfl_xor(nsum, 32);
  if (l == 0) {
    float num = nsum + start_trans[tg[0]] + end_trans[tg[L - 1]];
    atomicAdd(out, (logZ - num) * (1.f / 32.f));
  }
}

extern "C" void kernel_launch(void* const* d_in, const int* in_sizes, int n_in,
                              void* d_out, int out_size, void* d_ws, size_t ws_size,
                              hipStream_t stream) {
  (void)in_sizes; (void)n_in; (void)out_size;
  const float* sent        = (const float*)d_in[0];
  const int*   tags        = (const int*)d_in[1];
  const int*   lengths     = (const int*)d_in[2];
  // d_in[3] = mask (unused)
  const float* w_ih_f      = (const float*)d_in[4];
  const float* w_hh_f      = (const float*)d_in[5];
  const float* b_ih_f      = (const float*)d_in[6];
  const float* b_hh_f      = (const float*)d_in[7];
  const float* w_ih_b      = (const float*)d_in[8];
  const float* w_hh_b      = (const float*)d_in[9];
  const float* b_ih_b      = (const float*)d_in[10];
  const float* b_hh_b      = (const float*)d_in[11];
  const float* w_tag       = (const float*)d_in[12];
  const float* b_tag       = (const float*)d_in[13];
  const float* start_trans = (const float*)d_in[14];
  const float* end_trans   = (const float*)d_in[15];
  const float* trans       = (const float*)d_in[16];

  char* ws = (char*)d_ws;
  u64*    wh8    = (u64*)(ws + 0x000000);
  v8bf*   wt16   = (v8bf*)(ws + 0x080000);
  float*  biasp  = (float*)(ws + 0x084000);
  __bf16* hstate = (__bf16*)(ws + 0x086000);   // 32 KB (4 slots x 8 KB)
  float*  cstate = (float*)(ws + 0x08E000);    // 64 KB
  __bf16* emisF  = (__bf16*)(ws + 0x100000);
  __bf16* emisB  = (__bf16*)(ws + 0x200000);
  __bf16* pre    = (__bf16*)(ws + 0x300000);

  // largest CT whose double pre (CT*256KB) + double hbuf (CT*64KB) fits.
  int CT = 64;
  for (int cand : {256, 128}) {
    if ((size_t)0x300000 + (size_t)cand * (2 * 131072 + 2 * 32768) <= ws_size) { CT = cand; break; }
  }
  __bf16* hbuf = (__bf16*)(ws + 0x300000 + 2ull * (size_t)CT * 131072ull);
  const int TT = 32;
  const int nch = T_ / CT;
  const int NPREB = 128 * (CT / TT);   // 2 pre sub-units per block
  const int NEMIS = CT / 2;            // 8 emission waves per block
  dim3 grid(4 + NPREB + NEMIS, 1, 1);

  hipMemsetAsync(d_out, 0, sizeof(float), stream);
  prepack<<<364, 256, 0, stream>>>(w_hh_f, w_hh_b, b_ih_f, b_hh_f, b_ih_b, b_hh_b,
                                   w_tag, wh8, wt16, biasp, (u32*)hstate, cstate);
  // prime: pre for chunk 0 only
  fused_chunk<<<grid, 512, 0, stream>>>(sent, lengths, w_ih_f, w_ih_b, biasp, wh8, wt16,
                                        hstate, cstate, pre, hbuf, emisF, emisB,
                                        -1, 0, -1, CT, TT, nch, NPREB);
  for (int c = 0; c < nch; ++c)
    fused_chunk<<<grid, 512, 0, stream>>>(sent, lengths, w_ih_f, w_ih_b, biasp, wh8, wt16,
                                          hstate, cstate, pre, hbuf, emisF, emisB,
                                          c, c + 1, c - 1, CT, TT, nch, NPREB);
  // tail: emission for the last chunk
  fused_chunk<<<grid, 512, 0, stream>>>(sent, lengths, w_ih_f, w_ih_b, biasp, wh8, wt16,
                                        hstate, cstate, pre, hbuf, emisF, emisB,
                                        -1, nch, nch - 1, CT, TT, nch, NPREB);
  crf_pass<<<32, 64, 0, stream>>>(lengths, tags, b_tag, start_trans, end_trans, trans,
                                  emisF, emisB, (float*)d_out);
}